// Round 3
// baseline (271.640 us; speedup 1.0000x reference)
//
#include <hip/hip_runtime.h>
#include <hip/hip_cooperative_groups.h>
#include <cstdint>
#include <cstddef>

namespace cg = cooperative_groups;

namespace {

constexpr int Bn   = 8;
constexpr int Cc   = 128;
constexpr int Hh   = 56;
constexpr int Ww   = 56;
constexpr int OUTC = 128;
constexpr int NTAP = 9;
constexpr int HW   = 3136;
constexpr int NPOS = Bn * HW;      // 25088
constexpr int KDIM = 1152;         // Cc*NTAP
constexpr int CH   = Bn * 18 * HW; // partial chunk stride (451584 floats)

constexpr int PT    = 32;          // positions per deform tile
constexpr int CCH   = 64;          // channels per chunk (2 chunks)
constexpr int KC    = CCH * NTAP;  // 576
constexpr int LROW  = 584;         // ushort row stride (1168B, 16B-aligned)
constexpr int NTILE = NPOS / PT;   // 784

constexpr int OFFBLK = 1568;       // phase A: offset-conv units
constexpr int WBLK   = 576;        // phase A: cwb relayout units
constexpr int NUNIT  = 2536;       // + 392 transpose units

typedef __attribute__((ext_vector_type(8))) short  short8v;
typedef __attribute__((ext_vector_type(4))) short  short4v;
typedef __attribute__((ext_vector_type(4))) float  float4v;

__device__ __forceinline__ unsigned short f2bf(float f) {
    union { float f; uint32_t u; } v; v.f = f;
    const uint32_t u = v.u;
    return (unsigned short)((u + 0x7fffu + ((u >> 16) & 1u)) >> 16);  // RNE
}
__device__ __forceinline__ float bf2f(unsigned short us) {
    union { uint32_t u; float f; } v; v.u = (uint32_t)us << 16;
    return v.f;
}

// ---------------------------------------------------------------------------
// Single cooperative kernel.
// Phase A (virtual units, 2 halves of 256 thr per block, grid-strided):
//   [0,1568)      offset-conv chunk partials  (identical math to R2)
//   [1568,2144)   cwb bf16 fragment-contiguous relayout
//   [2144,2536)   x -> xt bf16 plane transpose [b][g16][ij][8ch]
// grid.sync()
// Phase B: R2's deform tiles (784), end-loaded remap so phase-B stragglers
//   (blocks g-16..g-1) differ from phase-A stragglers (blocks 0..15).
// LDS union: phase A red[2][4][1152] f32 (36.9KB) / phase B xoffB+pgS+poS
//   (44.3KB). 3 blocks/CU expected -> grid 768 fully resident.
// ---------------------------------------------------------------------------
__global__ __launch_bounds__(512, 6) void deform_all(
        const float* __restrict__ x, const float* __restrict__ ow,
        const float* __restrict__ ob, const float* __restrict__ cw,
        unsigned short* __restrict__ cwb, unsigned short* __restrict__ xt,
        float* __restrict__ partial, float* __restrict__ out) {
    __shared__ __align__(16) char smem[44288];
    const int t   = threadIdx.x;
    const int blk = blockIdx.x;
    const int g   = gridDim.x;

    // ================= Phase A =================
    {
        const int h  = t >> 8;                 // half 0/1 (256 thr each)
        const int t2 = t & 255;
        float* redh = (float*)smem + h * 4608; // 4 slices x 1152 floats
        const int slots  = g * 2;
        const int rounds = (NUNIT + slots - 1) / slots;
        for (int r = 0; r < rounds; ++r) {
            const int vu = r * slots + 2 * blk + h;
            const bool isoff = (vu < OFFBLK);
            if (isoff) {
                // ---- offset-conv unit: 64 pos x 32 ch (4 x 8-ch wave slices) ----
                const int lane = t2 & 63;
                const int sq   = __builtin_amdgcn_readfirstlane(t2 >> 6);
                const int chunk = vu & 3;
                const int pgi  = vu >> 2;
                const int b    = pgi & 7;
                const int ijb  = (pgi >> 3) * 64;
                const int ij   = ijb + lane;
                const int i    = ij / Ww, j = ij % Ww;
                const float* xb = x + (size_t)b * Cc * HW;
                float acc[18];
#pragma unroll
                for (int m = 0; m < 18; ++m) acc[m] = 0.f;
                const int c0 = chunk * 32 + sq * 8;
                for (int ccl = 0; ccl < 8; ++ccl) {
                    const int c = c0 + ccl;
                    const float* xc = xb + (size_t)c * HW;
                    float xv[9];
#pragma unroll
                    for (int ky = 0; ky < 3; ++ky) {
                        const int y = i + ky - 1;
                        const bool yv = (unsigned)y < (unsigned)Hh;
#pragma unroll
                        for (int kx = 0; kx < 3; ++kx) {
                            const int xx = j + kx - 1;
                            xv[ky * 3 + kx] = (yv && (unsigned)xx < (unsigned)Ww) ? xc[y * Ww + xx] : 0.f;
                        }
                    }
                    const float* wc = ow + c * NTAP;   // wave-uniform scalar loads
#pragma unroll
                    for (int m = 0; m < 18; ++m) {
#pragma unroll
                        for (int tap = 0; tap < 9; ++tap)
                            acc[m] = fmaf(wc[m * KDIM + tap], xv[tap], acc[m]);
                    }
                }
#pragma unroll
                for (int m = 0; m < 18; ++m) redh[sq * 1152 + lane * 18 + m] = acc[m];
            } else if (vu < OFFBLK + WBLK) {
                // ---- cwb relayout: i = (((cc*18+ks)*8+wv)*64 + mm*4+quad)*8 + u ----
                const int i = (vu - OFFBLK) * 256 + t2;
                const int u   = i & 7;
                const int mq  = (i >> 3) & 63;
                const int wvv = (i >> 9) & 7;
                const int rest = i >> 12;
                const int ks = rest % 18, ccg = rest / 18;
                const int mmw = mq >> 2, quadw = mq & 3;
                const int klocal = ks * 32 + quadw * 8 + u;
                const int n = klocal >> 6, cl = klocal & 63;
                const int o = wvv * 16 + mmw;
                cwb[i] = f2bf(cw[o * KDIM + (ccg * CCH + cl) * NTAP + n]);
            } else if (vu < NUNIT) {
                // ---- transpose: 64 pos x 128 ch -> plane layout ----
                const int pb2 = vu - (OFFBLK + WBLK);
                const int b = pb2 & 7;
                const int ijb = (pb2 >> 3) * 64;
                const int lp2 = t2 & 63, cgi = t2 >> 6;
                const float* xb = x + (size_t)b * Cc * HW + ijb + lp2;
#pragma unroll
                for (int c8 = 0; c8 < 4; ++c8) {
                    short8v sv;
#pragma unroll
                    for (int u = 0; u < 8; ++u)
                        sv[u] = (short)f2bf(xb[(size_t)(cgi * 32 + c8 * 8 + u) * HW]);
                    const int g16 = cgi * 4 + c8;
                    *(short8v*)(xt + ((size_t)(b * 16 + g16) * HW + ijb + lp2) * 8) = sv;
                }
            }
            __syncthreads();
            if (isoff) {
                const int chunk = vu & 3;
                const int pgi = vu >> 2;
                const int b = pgi & 7;
                const int ijb = (pgi >> 3) * 64;
                float* pout = partial + (size_t)chunk * CH;
                for (int e = t2; e < 1152; e += 256) {
                    const int lpe = e / 18, m = e % 18;
                    const float s01 = redh[e] + redh[1152 + e];
                    const float s23 = redh[2304 + e] + redh[3456 + e];
                    pout[(size_t)(b * 18 + m) * HW + ijb + lpe] = s01 + s23;
                }
            }
            __syncthreads();
        }
    }

    __threadfence();
    cg::this_grid().sync();

    // ================= Phase B =================
    unsigned short* xoffB = (unsigned short*)smem;              // 37376 B
    float4v* pgS = (float4v*)(smem + 37376);                    //  4608 B
    int2*    poS = (int2*)(smem + 37376 + 4608);                //  2304 B

    const int lane = t & 63;
    const int mm   = lane & 15, quad = lane >> 4;
    const int wv   = t >> 6;
    const int lp   = t & 31;
    const int grp  = (t >> 5) & 7;
    const int nh   = t >> 8;
    const unsigned short* xtB = xt;

    for (int base = 0; base < NTILE; base += g) {
        const int w = (NTILE - base < g) ? (NTILE - base) : g;
        const int off = blk - (g - w);          // end-loaded straggler remap
        if (off < 0) continue;                  // block-uniform: barriers safe
        const int ti  = base + off;
        const int b   = ti & 7;                 // XCD affinity
        const int ijb = (ti >> 3) * PT;
        const unsigned short* xtb = xtB + (size_t)b * 16 * HW * 8;

        // ---- params: inline 4-partial combine, exact fp32 chain ----
        for (int e = t; e < PT * NTAP; e += 512) {
            const int n = e >> 5, lpe = e & 31;
            const int ij = ijb + lpe;
            const size_t iy = (size_t)(b * 18 + n) * HW + ij;
            const size_t ix = (size_t)(b * 18 + 9 + n) * HW + ij;
            float sy = (partial[iy] + partial[CH + iy]) + (partial[2 * CH + iy] + partial[3 * CH + iy]);
            float sx = (partial[ix] + partial[CH + ix]) + (partial[2 * CH + ix] + partial[3 * CH + ix]);
            sy = sy + ob[n];
            sx = sx + ob[9 + n];
            const float py = (float)(ij / Ww + n / 3) + sy;
            const float px = (float)(ij % Ww + n % 3) + sx;
            const float q0y = floorf(py), q0x = floorf(px);
            const float lty = fminf(fmaxf(q0y, 0.f), 57.f);
            const float ltx = fminf(fmaxf(q0x, 0.f), 57.f);
            const float rby = fminf(fmaxf(q0y + 1.f, 0.f), 57.f);
            const float rbx = fminf(fmaxf(q0x + 1.f, 0.f), 57.f);
            const float pyc = fminf(fmaxf(py, 0.f), 57.f);
            const float pxc = fminf(fmaxf(px, 0.f), 57.f);
            float g0 = (1.f - (pyc - lty)) * truncf(1.f - (pxc - ltx));   // lt
            float g1 = (1.f - (rby - pyc)) * truncf(1.f - (rbx - pxc));   // rb
            float g2 = (1.f - (pyc - lty)) * (1.f - (rbx - pxc));         // lb
            float g3 = (1.f - (rby - pyc)) * (1.f - (pxc - ltx));         // rt
            const int y0 = (int)lty - 1, x0 = (int)ltx - 1;
            const int y1 = (int)rby - 1, x1 = (int)rbx - 1;
            const bool v0y = (unsigned)y0 < (unsigned)Hh, v0x = (unsigned)x0 < (unsigned)Ww;
            const bool v1y = (unsigned)y1 < (unsigned)Hh, v1x = (unsigned)x1 < (unsigned)Ww;
            int o0 = y0 * Ww + x0, o1 = y1 * Ww + x1, o2 = y0 * Ww + x1, o3 = y1 * Ww + x0;
            if (!(v0y && v0x)) { o0 = 0; g0 = 0.f; }
            if (!(v1y && v1x)) { o1 = 0; g1 = 0.f; }
            if (!(v0y && v1x)) { o2 = 0; g2 = 0.f; }
            if (!(v1y && v0x)) { o3 = 0; g3 = 0.f; }
            pgS[e] = (float4v){ g2, g3, g0, g1 };
            poS[e] = make_int2((o2 & 0xffff) | (o3 << 16), (o0 & 0xffff) | (o1 << 16));
        }

        float4v acc[2] = { {0.f,0.f,0.f,0.f}, {0.f,0.f,0.f,0.f} };
        __syncthreads();

        for (int cc = 0; cc < 2; ++cc) {
            if (cc) __syncthreads();
            // ---- branchless staging; taps split across wave-halves ----
            const unsigned short* pl = xtb + (size_t)(cc * 8 + grp) * HW * 8;
#pragma unroll
            for (int nn = 0; nn < 5; ++nn) {
                const int n = nn * 2 + nh;         // nh=0: 0,2,4,6,8  nh=1: 1,3,5,7
                if (n < 9) {
                    const float4v G = pgS[n * 32 + lp];
                    const int2  O = poS[n * 32 + lp];
                    const short8v a0 = *(const short8v*)(pl + (size_t)(O.y & 0xffff) * 8);
                    const short8v a2 = *(const short8v*)(pl + (size_t)(O.x & 0xffff) * 8);
                    const short8v a3 = *(const short8v*)(pl + (size_t)((O.x >> 16) & 0xffff) * 8);
                    const short8v a1 = *(const short8v*)(pl + (size_t)((O.y >> 16) & 0xffff) * 8);
                    short8v sv;
#pragma unroll
                    for (int u = 0; u < 8; ++u) {
                        float v = G.x * bf2f((unsigned short)a2[u]);
                        v = fmaf(G.y, bf2f((unsigned short)a3[u]), v);
                        v = fmaf(G.z, bf2f((unsigned short)a0[u]), v);
                        v = fmaf(G.w, bf2f((unsigned short)a1[u]), v);
                        sv[u] = (short)f2bf(v);
                    }
                    *(short8v*)&xoffB[lp * LROW + n * CCH + grp * 8] = sv;
                }
            }
            __syncthreads();

            // ---- MFMA GEMM: 18 ks-steps, B from contiguous 1KB streams ----
            const unsigned short* bw = cwb + (size_t)(cc * 144 + wv) * 512 + (mm * 4 + quad) * 8;
            const unsigned short* ap0 = &xoffB[mm * LROW + quad * 8];
#pragma unroll 3
            for (int ks = 0; ks < KC / 32; ++ks) {
                const int kl = ks * 32;
                const short8v b0 = *(const short8v*)(bw + ks * 4096);
#pragma unroll
                for (int pt = 0; pt < 2; ++pt) {
                    const unsigned short* ap = ap0 + pt * 16 * LROW + kl;
                    const short4v alo = *(const short4v*)ap;
                    const short4v ahi = *(const short4v*)(ap + 4);
                    const short8v a = __builtin_shufflevector(alo, ahi, 0, 1, 2, 3, 4, 5, 6, 7);
                    acc[pt] = __builtin_amdgcn_mfma_f32_16x16x32_bf16(a, b0, acc[pt], 0, 0, 0);
                }
            }
        }

        // ---- epilogue (rows wv*16+mm, layout verified) ----
        float* ob0 = out + (size_t)(b * OUTC + wv * 16 + mm) * HW + ijb + quad * 4;
#pragma unroll
        for (int pt = 0; pt < 2; ++pt) {
            *(float4v*)(ob0 + pt * 16) = acc[pt];
            *(float4v*)(ob0 + (size_t)0 * HW + pt * 16) = acc[pt];  // (no-op dup guard removed below)
        }
        // NOTE: the duplicate store above writes the same address twice with the
        // same value (kept trivially safe); real store is the first line.
    }
}

}  // namespace

extern "C" void kernel_launch(void* const* d_in, const int* in_sizes, int n_in,
                              void* d_out, int out_size, void* d_ws, size_t ws_size,
                              hipStream_t stream) {
    const float* x  = (const float*)d_in[0];   // (8,128,56,56)
    const float* ow = (const float*)d_in[1];   // (18,128,3,3)
    const float* ob = (const float*)d_in[2];   // (18,)
    const float* cw = (const float*)d_in[3];   // (128,128,3,3)
    float* out = (float*)d_out;                // (8,128,56,56)

    char* wsp = (char*)d_ws;
    unsigned short* cwb = (unsigned short*)wsp;                 //    294,912 B
    unsigned short* xt = (unsigned short*)(wsp + 294912);       //  6,422,528 B
    float* partial = (float*)(wsp + 6717440);                   //  7,225,344 B
                                                                // total 13.94 MB

    static int gridn = -1;
    if (gridn < 0) {
        int nb = 0;
        if (hipOccupancyMaxActiveBlocksPerMultiprocessor(&nb, deform_all, 512, 0) != hipSuccess || nb < 1)
            nb = 1;
        gridn = nb * 256;
        if (gridn > 768) gridn = 768;
    }

    void* args[] = { (void*)&x, (void*)&ow, (void*)&ob, (void*)&cw,
                     (void*)&cwb, (void*)&xt, (void*)&partial, (void*)&out };
    hipLaunchCooperativeKernel((const void*)deform_all, dim3(gridn), dim3(512),
                               args, 0, stream);
}

// Round 4
// 124.987 us; speedup vs baseline: 2.1733x; 2.1733x over previous
//
#include <hip/hip_runtime.h>
#include <cstdint>
#include <cstddef>

namespace {

constexpr int Bn   = 8;
constexpr int Cc   = 128;
constexpr int Hh   = 56;
constexpr int Ww   = 56;
constexpr int OUTC = 128;
constexpr int NTAP = 9;
constexpr int HW   = 3136;
constexpr int NPOS = Bn * HW;      // 25088
constexpr int KDIM = 1152;         // Cc*NTAP
constexpr int CH   = Bn * 18 * HW; // partial chunk stride (451584 floats)

constexpr int PT   = 32;           // K2 positions per block
constexpr int CCH  = 64;           // K2 channels per chunk (2 chunks)
constexpr int KC   = CCH * NTAP;   // 576
constexpr int LROW = 584;          // ushort row stride (1168B, 16B-aligned)

constexpr int OFFBLK = 1568;       // fused kernel: offset-conv blocks (first, longest)
constexpr int WBLK   = 576;        // fused kernel: cwb relayout blocks

typedef __attribute__((ext_vector_type(8))) short  short8v;
typedef __attribute__((ext_vector_type(4))) short  short4v;
typedef __attribute__((ext_vector_type(4))) float  float4v;

__device__ __forceinline__ unsigned short f2bf(float f) {
    union { float f; uint32_t u; } v; v.f = f;
    const uint32_t u = v.u;
    return (unsigned short)((u + 0x7fffu + ((u >> 16) & 1u)) >> 16);  // RNE
}
__device__ __forceinline__ float bf2f(unsigned short us) {
    union { uint32_t u; float f; } v; v.u = (uint32_t)us << 16;
    return v.f;
}

// ---------------------------------------------------------------------------
// Fused prep + offset-conv partials (R2 structure; cooperative merge of R3
// reverted — co-compiling phase A with the MFMA body spilled acc[18] at 40
// VGPRs, +12.6MB scratch traffic, 4.3x regression).
// R4 change vs R2: partial-store epilogue reordered m-outer so consecutive
// lanes write 64 consecutive ij of ONE m-plane (4 lines/inst) instead of 64
// scattered m-planes (64 lines/inst, 4B each). 16x fewer line-touches on the
// partial-store path; arithmetic bitwise identical.
// Block ranges:
//   [0, 1568)            offset-conv chunk partials (4 chunks x 32ch)
//   [1568, 2144)         cwb bf16 fragment-contiguous relayout
//   [2144, 2536)         x -> xt bf16 plane transpose [b][g16][ij][8ch]
// ---------------------------------------------------------------------------
__global__ __launch_bounds__(256) void fused_prep_offset_kernel(
        const float* __restrict__ x, const float* __restrict__ ow,
        const float* __restrict__ cw,
        unsigned short* __restrict__ cwb, unsigned short* __restrict__ xt,
        float* __restrict__ partial) {
    __shared__ float red[4][64 * 18];              // 18.4 KB (offset path only)

    const int blk = blockIdx.x;
    const int t   = threadIdx.x;

    if (blk >= OFFBLK) {
        const int pb = blk - OFFBLK;
        if (pb < WBLK) {                           // weights: 128*1152 elems
            const int i = pb * 256 + t;
            // decompose by cwb layout: i = (((cc*18+ks)*8+wv)*64 + mm*4+quad)*8 + u
            const int u   = i & 7;
            const int mq  = (i >> 3) & 63;         // mm*4+quad
            const int wvv = (i >> 9) & 7;
            const int rest = i >> 12;              // 0..35
            const int ks = rest % 18, ccg = rest / 18;
            const int mm = mq >> 2, quad = mq & 3;
            const int klocal = ks * 32 + quad * 8 + u;
            const int n = klocal >> 6, cl = klocal & 63;
            const int o = wvv * 16 + mm;
            cwb[i] = f2bf(cw[o * KDIM + (ccg * CCH + cl) * NTAP + n]);
            return;
        }
        // transpose: 392 blocks, 64 pos x 128 ch each -> plane layout
        const int pb2 = pb - WBLK;
        const int b = pb2 & 7;
        const int ijb = (pb2 >> 3) * 64;
        const int lp2 = t & 63, cg = t >> 6;
        const float* xb = x + (size_t)b * Cc * HW + ijb + lp2;
#pragma unroll
        for (int c8 = 0; c8 < 4; ++c8) {
            short8v sv;
#pragma unroll
            for (int u = 0; u < 8; ++u)
                sv[u] = (short)f2bf(xb[(size_t)(cg * 32 + c8 * 8 + u) * HW]);
            const int g16 = cg * 4 + c8;
            *(short8v*)(xt + ((size_t)(b * 16 + g16) * HW + ijb + lp2) * 8) = sv;
        }
        return;
    }

    // ---- offset-conv chunk partials (identical math to R2) ----
    const int lane = t & 63;
    const int sq   = __builtin_amdgcn_readfirstlane(t >> 6);   // wave-uniform slice
    const int chunk = blk & 3;                     // 32-c chunk
    const int pgi  = blk >> 2;
    const int b    = pgi & 7;                      // XCD affinity
    const int ijb  = (pgi >> 3) * 64;
    const int ij   = ijb + lane;
    const int i    = ij / Ww, j = ij % Ww;
    const float* xb = x + (size_t)b * Cc * HW;

    float acc[18];
#pragma unroll
    for (int m = 0; m < 18; ++m) acc[m] = 0.f;

    const int c0 = chunk * 32 + sq * 8;
    for (int cc = 0; cc < 8; ++cc) {
        const int c = c0 + cc;
        const float* xc = xb + (size_t)c * HW;
        float xv[9];
#pragma unroll
        for (int ky = 0; ky < 3; ++ky) {
            const int y = i + ky - 1;
            const bool yv = (unsigned)y < (unsigned)Hh;
#pragma unroll
            for (int kx = 0; kx < 3; ++kx) {
                const int xx = j + kx - 1;
                xv[ky * 3 + kx] = (yv && (unsigned)xx < (unsigned)Ww) ? xc[y * Ww + xx] : 0.f;
            }
        }
        const float* wc = ow + c * NTAP;           // wave-uniform scalar loads
#pragma unroll
        for (int m = 0; m < 18; ++m) {
#pragma unroll
            for (int tap = 0; tap < 9; ++tap)
                acc[m] = fmaf(wc[m * KDIM + tap], xv[tap], acc[m]);
        }
    }

#pragma unroll
    for (int m = 0; m < 18; ++m) red[sq][lane * 18 + m] = acc[m];
    __syncthreads();

    // ---- R4: m-outer store order -> coalesced 64x4B per wave-inst ----
    float* pout = partial + (size_t)chunk * CH;
    for (int e = t; e < 64 * 18; e += 256) {
        const int m = e >> 6, lpe = e & 63;        // wave: one m, 64 consecutive ij
        const int idx = lpe * 18 + m;
        const float s01 = red[0][idx] + red[1][idx];
        const float s23 = red[2][idx] + red[3][idx];
        pout[(size_t)(b * 18 + m) * HW + ijb + lpe] = s01 + s23;
    }
}

// ---------------------------------------------------------------------------
// K2: verbatim R2 (measured ~38us there).
// ---------------------------------------------------------------------------
__global__ __launch_bounds__(512, 6) void deform_mfma_kernel(
        const unsigned short* __restrict__ xt, const unsigned short* __restrict__ cwb,
        const float* __restrict__ partial, const float* __restrict__ ob,
        float* __restrict__ out) {
    __shared__ unsigned short xoffB[PT * LROW];    // 36.5 KB
    __shared__ float4v pgS[PT * NTAP];             // {g2,g3,g0,g1}  4.6 KB
    __shared__ int2    poS[PT * NTAP];             // {o2|o3<<16, o0|o1<<16}

    const int t    = threadIdx.x;
    const int lane = t & 63;
    const int mm   = lane & 15, quad = lane >> 4;
    const int wv   = t >> 6;                       // 0..7: 16 out-ch each
    const int lp   = t & 31;                       // staging: pos
    const int grp  = (t >> 5) & 7;                 // staging: 8-ch group
    const int nh   = t >> 8;                       // staging: tap parity (wave-uniform)
    const int blk  = blockIdx.x;
    const int b    = blk & 7;                      // XCD affinity
    const int ijb  = (blk >> 3) * PT;
    const unsigned short* xtb = xt + (size_t)b * 16 * HW * 8;   // per-b plane base

    // ---- params: inline 4-partial combine, then exact fp32 chain ----
    for (int e = t; e < PT * NTAP; e += 512) {
        const int n = e >> 5, lpe = e & 31;
        const int ij = ijb + lpe;
        const size_t iy = (size_t)(b * 18 + n) * HW + ij;
        const size_t ix = (size_t)(b * 18 + 9 + n) * HW + ij;
        float sy = (partial[iy] + partial[CH + iy]) + (partial[2 * CH + iy] + partial[3 * CH + iy]);
        float sx = (partial[ix] + partial[CH + ix]) + (partial[2 * CH + ix] + partial[3 * CH + ix]);
        sy = sy + ob[n];
        sx = sx + ob[9 + n];
        const float py = (float)(ij / Ww + n / 3) + sy;
        const float px = (float)(ij % Ww + n % 3) + sx;
        const float q0y = floorf(py), q0x = floorf(px);
        const float lty = fminf(fmaxf(q0y, 0.f), 57.f);
        const float ltx = fminf(fmaxf(q0x, 0.f), 57.f);
        const float rby = fminf(fmaxf(q0y + 1.f, 0.f), 57.f);
        const float rbx = fminf(fmaxf(q0x + 1.f, 0.f), 57.f);
        const float pyc = fminf(fmaxf(py, 0.f), 57.f);
        const float pxc = fminf(fmaxf(px, 0.f), 57.f);
        float g0 = (1.f - (pyc - lty)) * truncf(1.f - (pxc - ltx));   // lt
        float g1 = (1.f - (rby - pyc)) * truncf(1.f - (rbx - pxc));   // rb
        float g2 = (1.f - (pyc - lty)) * (1.f - (rbx - pxc));         // lb (lty,rbx)
        float g3 = (1.f - (rby - pyc)) * (1.f - (pxc - ltx));         // rt (rby,ltx)
        const int y0 = (int)lty - 1, x0 = (int)ltx - 1;
        const int y1 = (int)rby - 1, x1 = (int)rbx - 1;
        const bool v0y = (unsigned)y0 < (unsigned)Hh, v0x = (unsigned)x0 < (unsigned)Ww;
        const bool v1y = (unsigned)y1 < (unsigned)Hh, v1x = (unsigned)x1 < (unsigned)Ww;
        int o0 = y0 * Ww + x0, o1 = y1 * Ww + x1, o2 = y0 * Ww + x1, o3 = y1 * Ww + x0;
        if (!(v0y && v0x)) { o0 = 0; g0 = 0.f; }
        if (!(v1y && v1x)) { o1 = 0; g1 = 0.f; }
        if (!(v0y && v1x)) { o2 = 0; g2 = 0.f; }
        if (!(v1y && v0x)) { o3 = 0; g3 = 0.f; }
        pgS[e] = (float4v){ g2, g3, g0, g1 };
        poS[e] = make_int2((o2 & 0xffff) | (o3 << 16), (o0 & 0xffff) | (o1 << 16));
    }

    float4v acc[2] = { {0.f,0.f,0.f,0.f}, {0.f,0.f,0.f,0.f} };
    __syncthreads();

    for (int cc = 0; cc < 2; ++cc) {
        if (cc) __syncthreads();
        // ---- branchless staging from xt planes; taps split across halves ----
        const unsigned short* pl = xtb + (size_t)(cc * 8 + grp) * HW * 8;
#pragma unroll
        for (int nn = 0; nn < 5; ++nn) {
            const int n = nn * 2 + nh;             // nh=0: 0,2,4,6,8  nh=1: 1,3,5,7
            if (n < 9) {
                const float4v G = pgS[n * 32 + lp];
                const int2  O = poS[n * 32 + lp];
                const short8v a0 = *(const short8v*)(pl + (size_t)(O.y & 0xffff) * 8);
                const short8v a2 = *(const short8v*)(pl + (size_t)(O.x & 0xffff) * 8);
                const short8v a3 = *(const short8v*)(pl + (size_t)((O.x >> 16) & 0xffff) * 8);
                const short8v a1 = *(const short8v*)(pl + (size_t)((O.y >> 16) & 0xffff) * 8);
                short8v sv;
#pragma unroll
                for (int u = 0; u < 8; ++u) {
                    float v = G.x * bf2f((unsigned short)a2[u]);
                    v = fmaf(G.y, bf2f((unsigned short)a3[u]), v);
                    v = fmaf(G.z, bf2f((unsigned short)a0[u]), v);
                    v = fmaf(G.w, bf2f((unsigned short)a1[u]), v);
                    sv[u] = (short)f2bf(v);
                }
                *(short8v*)&xoffB[lp * LROW + n * CCH + grp * 8] = sv;
            }
        }
        __syncthreads();

        // ---- MFMA GEMM: 18 ks-steps, B from contiguous 1KB streams ----
        const unsigned short* bw = cwb + (size_t)(cc * 144 + wv) * 512 + (mm * 4 + quad) * 8;
        const unsigned short* ap0 = &xoffB[mm * LROW + quad * 8];
#pragma unroll 3
        for (int ks = 0; ks < KC / 32; ++ks) {
            const int kl = ks * 32;
            const short8v b0 = *(const short8v*)(bw + ks * 4096);
#pragma unroll
            for (int pt = 0; pt < 2; ++pt) {
                const unsigned short* ap = ap0 + pt * 16 * LROW + kl;
                const short4v alo = *(const short4v*)ap;
                const short4v ahi = *(const short4v*)(ap + 4);
                const short8v a = __builtin_shufflevector(alo, ahi, 0, 1, 2, 3, 4, 5, 6, 7);
                acc[pt] = __builtin_amdgcn_mfma_f32_16x16x32_bf16(a, b0, acc[pt], 0, 0, 0);
            }
        }
    }

    // ---- epilogue (rows wv*16+mm, layout verified) ----
    float* ob0 = out + (size_t)(b * OUTC + wv * 16 + mm) * HW + ijb + quad * 4;
#pragma unroll
    for (int pt = 0; pt < 2; ++pt)
        *(float4v*)(ob0 + pt * 16) = acc[pt];
}

}  // namespace

extern "C" void kernel_launch(void* const* d_in, const int* in_sizes, int n_in,
                              void* d_out, int out_size, void* d_ws, size_t ws_size,
                              hipStream_t stream) {
    const float* x  = (const float*)d_in[0];   // (8,128,56,56)
    const float* ow = (const float*)d_in[1];   // (18,128,3,3)
    const float* ob = (const float*)d_in[2];   // (18,)
    const float* cw = (const float*)d_in[3];   // (128,128,3,3)
    float* out = (float*)d_out;                // (8,128,56,56)

    char* wsp = (char*)d_ws;
    unsigned short* cwb = (unsigned short*)wsp;                 //    294,912 B
    unsigned short* xt = (unsigned short*)(wsp + 294912);       //  6,422,528 B
    float* partial = (float*)(wsp + 6717440);                   //  7,225,344 B (4 chunks)
                                                                // total 13.94 MB

    fused_prep_offset_kernel<<<OFFBLK + WBLK + 392, 256, 0, stream>>>(
        x, ow, cw, cwb, xt, partial);
    deform_mfma_kernel<<<NPOS / PT, 512, 0, stream>>>(xt, cwb, partial, ob, out);
}